// Round 14
// baseline (309.816 us; speedup 1.0000x reference)
//
#include <hip/hip_runtime.h>
#include <math.h>

#define DIN   32
#define F1    64   // H1*C1
#define F2    64   // H2*C2

// bf16 round-to-nearest-even pack of two floats into one uint
__device__ __forceinline__ unsigned bf16pack(float a, float b) {
    unsigned ua = __float_as_uint(a);
    unsigned ub = __float_as_uint(b);
    ua = (ua + 0x7FFFu + ((ua >> 16) & 1u)) >> 16;
    ub = (ub + 0x7FFFu + ((ub >> 16) & 1u)) >> 16;
    return ua | (ub << 16);
}

// ---------------- dense-linear body (shared) --------------------------------
// 32-node x 128-output tile, 256 threads, 2x8 micro-tile (16 acc regs).
// R4/R5 lesson: fatter micro-tiles spill to scratch; cap unroll.
template <int K>
__device__ __forceinline__ void lin_lr_body(int bid,
        const float* __restrict__ x,
        const float* __restrict__ Wl, const float* __restrict__ bl,
        const float* __restrict__ Wr, const float* __restrict__ br,
        float* __restrict__ xl, float* __restrict__ xr, int n) {
    __shared__ float Ash[32][K + 4];
    __shared__ float Wsh[K][128];
    const int t = threadIdx.x;
    const int node0 = bid * 32;

    for (int idx = t; idx < 32 * (K / 4); idx += 256) {
        int m = idx / (K / 4), kq = idx % (K / 4);
        float4 v = make_float4(0.f, 0.f, 0.f, 0.f);
        if (node0 + m < n) v = ((const float4*)(x + (size_t)(node0 + m) * K))[kq];
        *(float4*)&Ash[m][kq * 4] = v;
    }
    for (int idx = t; idx < K * 32; idx += 256) {
        int k = idx / 32, j4 = idx % 32;
        float4 v = (j4 < 16) ? ((const float4*)(Wl + (size_t)k * 64))[j4]
                             : ((const float4*)(Wr + (size_t)k * 64))[j4 - 16];
        *(float4*)&Wsh[k][j4 * 4] = v;
    }
    __syncthreads();

    const int ty = t >> 4;
    const int tx = t & 15;
    float acc0[8], acc1[8];
#pragma unroll
    for (int j = 0; j < 8; j++) { acc0[j] = 0.f; acc1[j] = 0.f; }

#pragma unroll 4
    for (int k = 0; k < K; k++) {
        float a0 = Ash[ty * 2 + 0][k];
        float a1 = Ash[ty * 2 + 1][k];
        float4 w0 = *(const float4*)&Wsh[k][tx * 8];
        float4 w1 = *(const float4*)&Wsh[k][tx * 8 + 4];
        acc0[0] += a0 * w0.x; acc0[1] += a0 * w0.y;
        acc0[2] += a0 * w0.z; acc0[3] += a0 * w0.w;
        acc0[4] += a0 * w1.x; acc0[5] += a0 * w1.y;
        acc0[6] += a0 * w1.z; acc0[7] += a0 * w1.w;
        acc1[0] += a1 * w0.x; acc1[1] += a1 * w0.y;
        acc1[2] += a1 * w0.z; acc1[3] += a1 * w0.w;
        acc1[4] += a1 * w1.x; acc1[5] += a1 * w1.y;
        acc1[6] += a1 * w1.z; acc1[7] += a1 * w1.w;
    }

    const float* bsrc = (tx < 8) ? bl : br;
    int jb = (tx < 8) ? tx * 8 : (tx - 8) * 8;
    float4 b0 = ((const float4*)(bsrc + jb))[0];
    float4 b1 = ((const float4*)(bsrc + jb))[1];
    float* dst = (tx < 8) ? xl : xr;
#pragma unroll
    for (int m = 0; m < 2; m++) {
        int node = node0 + ty * 2 + m;
        if (node >= n) continue;
        const float* ac = (m == 0) ? acc0 : acc1;
        float4 o0, o1;
        o0.x = ac[0] + b0.x; o0.y = ac[1] + b0.y;
        o0.z = ac[2] + b0.z; o0.w = ac[3] + b0.w;
        o1.x = ac[4] + b1.x; o1.y = ac[5] + b1.y;
        o1.z = ac[6] + b1.z; o1.w = ac[7] + b1.w;
        ((float4*)(dst + (size_t)node * 64 + jb))[0] = o0;
        ((float4*)(dst + (size_t)node * 64 + jb))[1] = o1;
    }
}

// ---------------- K1: bucket-count + rank + cursor reserve || lin1 ----------
__global__ __launch_bounds__(256, 2)
void fused_bcount_lin1(const int* __restrict__ dstr, int* __restrict__ cursor,
                       int* __restrict__ chunkoff, int* __restrict__ rank,
                       int E, int Ec, int NB, int gridLin,
                       const float* __restrict__ x,
                       const float* __restrict__ Wl, const float* __restrict__ bl,
                       const float* __restrict__ Wr, const float* __restrict__ br,
                       float* __restrict__ xl, float* __restrict__ xr, int n) {
    __shared__ int hist[256];
    if ((int)blockIdx.x < gridLin) {
        lin_lr_body<DIN>(blockIdx.x, x, Wl, bl, Wr, br, xl, xr, n);
        return;
    }
    const int blk = blockIdx.x - gridLin;
    const int t = threadIdx.x;
    hist[t] = 0;
    __syncthreads();
    const int s0 = blk * Ec, s1 = min(E, s0 + Ec);
    for (int e = s0 + t; e < s1; e += 256)
        rank[e] = atomicAdd(&hist[dstr[e] >> 8], 1);
    __syncthreads();
    if (t < NB) {
        int h = hist[t];
        chunkoff[blk * 256 + t] = h ? atomicAdd(&cursor[t], h) : 0;
    }
}

// ---------------- K3: scatter into fixed-cap bucket regions -----------------
__global__ __launch_bounds__(512)
void scatter_buckets(const int* __restrict__ srcr, const int* __restrict__ dstr,
                     const float* __restrict__ ea, const int* __restrict__ rank,
                     const int* __restrict__ chunkoff,
                     int2* __restrict__ inter, int E, int Ec, int NB, int cap) {
    __shared__ int colsh[256];
    const int blk = blockIdx.x;
    const int t = threadIdx.x;
    if (t < 256) colsh[t] = (t < NB) ? (t * cap + chunkoff[blk * 256 + t]) : 0;
    __syncthreads();
    const int s0 = blk * Ec, s1 = min(E, s0 + Ec);
    for (int e = s0 + t; e < s1; e += 512) {
        int d = dstr[e];
        float2 v = ((const float2*)ea)[e];
        int2 r;
        r.x = srcr[e] | ((d & 255) << 24);
        r.y = (int)bf16pack(v.x, v.y);
        inter[colsh[d >> 8] + rank[e]] = r;
    }
}

// ---------------- K4: per-bucket CSR finalize (TB=512) ----------------------
// Also accumulates per-node edge-attr sums (LDS float atomics) and writes the
// self-loop MEAN to la2[node] — gat drops its s0/s1/divide entirely (R14).
// rse[node] = {start, end}. Gaps zeroed so gat prefetches are safe.
__global__ __launch_bounds__(512)
void bucket_csr(const int2* __restrict__ inter, const int* __restrict__ cursor,
                int2* __restrict__ rse, float2* __restrict__ la2,
                int2* __restrict__ edges, int NB, int N, int cap) {
    __shared__ int sh[256];
    __shared__ int cur[256];
    __shared__ float las0[256];
    __shared__ float las1[256];
    const int b = blockIdx.x, t = threadIdx.x;
    const int bstart = b * cap;
    const int bend = bstart + cursor[b];

    if (t < 256) { sh[t] = 0; las0[t] = 0.f; las1[t] = 0.f; }
    __syncthreads();
    for (int pos = bstart + t; pos < bend; pos += 512) {
        int2 rec = inter[pos];
        int nd = ((unsigned)rec.x) >> 24;
        atomicAdd(&sh[nd], 1);
        atomicAdd(&las0[nd], __int_as_float(rec.y << 16));
        atomicAdd(&las1[nd], __int_as_float(rec.y & 0xFFFF0000));
    }
    __syncthreads();
    int v = 0;
    if (t < 256) v = sh[t];
    __syncthreads();
    if (t < 256) sh[t] = v;
    __syncthreads();
    for (int off = 1; off < 256; off <<= 1) {
        int x = (t >= off && t < 256) ? sh[t - off] : 0;
        __syncthreads();
        if (t < 256) sh[t] += x;
        __syncthreads();
    }
    if (t < 256) {
        int excl = sh[t] - v;
        cur[t] = excl;
        int node = b * 256 + t;
        if (node < N) {
            rse[node] = make_int2(bstart + excl, bstart + excl + v);
            float inv = v ? 1.0f / (float)v : 0.f;
            la2[node] = make_float2(las0[t] * inv, las1[t] * inv);
        }
    }
    __syncthreads();
    for (int pos = bstart + t; pos < bend; pos += 512) {
        int2 r = inter[pos];
        int k = atomicAdd(&cur[((unsigned)r.x) >> 24], 1);
        r.x &= 0x00FFFFFF;                      // strip dst byte for gat
        edges[bstart + k] = r;
    }
    // zero the gap so gat prefetches past re[] read {src=0, ea=0} records
    int zend = (b + 1) * cap + ((b == NB - 1) ? 64 : 0);
    for (int pos = bend + t; pos < zend; pos += 512)
        edges[pos] = make_int2(0, 0);
}

__global__ __launch_bounds__(256, 2)
void lin_lr_tiled64(const float* __restrict__ x,
                    const float* __restrict__ Wl, const float* __restrict__ bl,
                    const float* __restrict__ Wr, const float* __restrict__ br,
                    float* __restrict__ xl, float* __restrict__ xr, int n) {
    lin_lr_body<F1>(blockIdx.x, x, Wl, bl, Wr, br, xl, xr, n);
}

// ---------------- GATv2 edge phase ------------------------------------------
// R14: remainder-FIRST masked head (deg mod 8 edges), then a completely
// mask-free main loop (no bool/select per iter). Self-loop mean precomputed
// in bucket_csr (la2) — no s0/s1, no divide. 8 edges/iter, two independent
// prefetch streams (R10). Max-free online softmax (logits bounded).
template <int H, int C, bool FUSE_HEADS>
__global__ __launch_bounds__(256)
void gat_kernel(const float* __restrict__ xl, const float* __restrict__ xr,
                const int2* __restrict__ rse, const float2* __restrict__ la2,
                const int2* __restrict__ edges,
                const float* __restrict__ We, const float* __restrict__ att,
                const float* __restrict__ bias, float* __restrict__ hout,
                const float* __restrict__ wa, const float* __restrict__ ba,
                const float* __restrict__ wc, const float* __restrict__ bc,
                const float* __restrict__ ls, float* __restrict__ pout,
                int n) {
    constexpr int LPH = C / 4;
    if (FUSE_HEADS && blockIdx.x == 0 && threadIdx.x < 2)
        pout[(size_t)n * 2 + threadIdx.x] = expf(ls[threadIdx.x]);
    const int lane = threadIdx.x & 63;
    const int wid = (blockIdx.x * blockDim.x + threadIdx.x) >> 6;
    if (wid >= n) return;
    const int i = wid;
    const int g = lane >> 4;
    const int q = lane & 15;

    const float4* xl4 = (const float4*)xl;
    const float4 xri = ((const float4*)(xr + (size_t)i * 64))[q];
    const float4 we0 = ((const float4*)We)[q];
    const float4 we1 = ((const float4*)(We + 64))[q];
    float4 av = ((const float4*)att)[q];
    const float LOG2E = 1.4426950408889634f;
    av.x *= LOG2E; av.y *= LOG2E; av.z *= LOG2E; av.w *= LOG2E;

    float den = 0.f;
    float a0 = 0.f, a1 = 0.f, a2 = 0.f, a3 = 0.f;

    const int2 se = rse[i];
    const int e0 = se.x, e1 = se.y;
    const int r = (e1 - e0) & 7;

    // ---- masked head: the (deg mod 8) ragged edges, done FIRST ----
    if (r) {
        int2 h0 = edges[e0 + g];
        int2 h1 = edges[e0 + 4 + g];
        float4 xh0 = xl4[(h0.x << 4) + q];
        float4 xh1 = xl4[(h1.x << 4) + q];
        const bool v0 = g < r;
        const bool v1 = (4 + g) < r;
        float ea00 = v0 ? __int_as_float(h0.y << 16) : 0.f;
        float ea01 = v0 ? __int_as_float(h0.y & 0xFFFF0000) : 0.f;
        float ea10 = v1 ? __int_as_float(h1.y << 16) : 0.f;
        float ea11 = v1 ? __int_as_float(h1.y & 0xFFFF0000) : 0.f;
        float y0 = xh0.x + fmaf(ea00, we0.x, fmaf(ea01, we1.x, xri.x));
        float y1 = xh0.y + fmaf(ea00, we0.y, fmaf(ea01, we1.y, xri.y));
        float y2 = xh0.z + fmaf(ea00, we0.z, fmaf(ea01, we1.z, xri.z));
        float y3 = xh0.w + fmaf(ea00, we0.w, fmaf(ea01, we1.w, xri.w));
        float u0 = xh1.x + fmaf(ea10, we0.x, fmaf(ea11, we1.x, xri.x));
        float u1 = xh1.y + fmaf(ea10, we0.y, fmaf(ea11, we1.y, xri.y));
        float u2 = xh1.z + fmaf(ea10, we0.z, fmaf(ea11, we1.z, xri.z));
        float u3 = xh1.w + fmaf(ea10, we0.w, fmaf(ea11, we1.w, xri.w));
        y0 = fmaxf(y0, 0.2f * y0); u0 = fmaxf(u0, 0.2f * u0);
        y1 = fmaxf(y1, 0.2f * y1); u1 = fmaxf(u1, 0.2f * u1);
        y2 = fmaxf(y2, 0.2f * y2); u2 = fmaxf(u2, 0.2f * u2);
        y3 = fmaxf(y3, 0.2f * y3); u3 = fmaxf(u3, 0.2f * u3);
        float l0 = fmaf(y0, av.x, fmaf(y1, av.y, fmaf(y2, av.z, y3 * av.w)));
        float l1 = fmaf(u0, av.x, fmaf(u1, av.y, fmaf(u2, av.z, u3 * av.w)));
#pragma unroll
        for (int m = 1; m < LPH; m <<= 1) {
            l0 += __shfl_xor(l0, m, 64);
            l1 += __shfl_xor(l1, m, 64);
        }
        float p0 = v0 ? exp2f(l0) : 0.f;
        float p1 = v1 ? exp2f(l1) : 0.f;
        den += p0 + p1;
        a0 = fmaf(p0, xh0.x, fmaf(p1, xh1.x, a0));
        a1 = fmaf(p0, xh0.y, fmaf(p1, xh1.y, a1));
        a2 = fmaf(p0, xh0.z, fmaf(p1, xh1.z, a2));
        a3 = fmaf(p0, xh0.w, fmaf(p1, xh1.w, a3));
    }

    // ---- mask-free main loop (multiple of 8 edges) ----
    const int em = e0 + r;
    int2 rn0 = edges[em + g];
    int2 rn1 = edges[em + 4 + g];
    float4 xvn0 = xl4[(rn0.x << 4) + q];
    float4 xvn1 = xl4[(rn1.x << 4) + q];

    for (int eb = em; eb < e1; eb += 8) {
        int2 r0 = rn0, r1 = rn1;
        float4 xv0 = xvn0, xv1 = xvn1;
        rn0 = edges[eb + 8 + g];
        rn1 = edges[eb + 12 + g];
        xvn0 = xl4[(rn0.x << 4) + q];
        xvn1 = xl4[(rn1.x << 4) + q];

        float ea00 = __int_as_float(r0.y << 16);
        float ea01 = __int_as_float(r0.y & 0xFFFF0000);
        float ea10 = __int_as_float(r1.y << 16);
        float ea11 = __int_as_float(r1.y & 0xFFFF0000);

        float y0 = xv0.x + fmaf(ea00, we0.x, fmaf(ea01, we1.x, xri.x));
        float y1 = xv0.y + fmaf(ea00, we0.y, fmaf(ea01, we1.y, xri.y));
        float y2 = xv0.z + fmaf(ea00, we0.z, fmaf(ea01, we1.z, xri.z));
        float y3 = xv0.w + fmaf(ea00, we0.w, fmaf(ea01, we1.w, xri.w));
        float u0 = xv1.x + fmaf(ea10, we0.x, fmaf(ea11, we1.x, xri.x));
        float u1 = xv1.y + fmaf(ea10, we0.y, fmaf(ea11, we1.y, xri.y));
        float u2 = xv1.z + fmaf(ea10, we0.z, fmaf(ea11, we1.z, xri.z));
        float u3 = xv1.w + fmaf(ea10, we0.w, fmaf(ea11, we1.w, xri.w));
        y0 = fmaxf(y0, 0.2f * y0); u0 = fmaxf(u0, 0.2f * u0);
        y1 = fmaxf(y1, 0.2f * y1); u1 = fmaxf(u1, 0.2f * u1);
        y2 = fmaxf(y2, 0.2f * y2); u2 = fmaxf(u2, 0.2f * u2);
        y3 = fmaxf(y3, 0.2f * y3); u3 = fmaxf(u3, 0.2f * u3);
        float l0 = fmaf(y0, av.x, fmaf(y1, av.y, fmaf(y2, av.z, y3 * av.w)));
        float l1 = fmaf(u0, av.x, fmaf(u1, av.y, fmaf(u2, av.z, u3 * av.w)));
#pragma unroll
        for (int m = 1; m < LPH; m <<= 1) {
            l0 += __shfl_xor(l0, m, 64);
            l1 += __shfl_xor(l1, m, 64);
        }
        float p0 = exp2f(l0);
        float p1 = exp2f(l1);
        den += p0 + p1;
        a0 = fmaf(p0, xv0.x, fmaf(p1, xv1.x, a0));
        a1 = fmaf(p0, xv0.y, fmaf(p1, xv1.y, a1));
        a2 = fmaf(p0, xv0.z, fmaf(p1, xv1.z, a2));
        a3 = fmaf(p0, xv0.w, fmaf(p1, xv1.w, a3));
    }

    // merge the 4 edge-slot groups — pure adds
#pragma unroll
    for (int m = 16; m < 64; m <<= 1) {
        den += __shfl_xor(den, m, 64);
        a0 += __shfl_xor(a0, m, 64);
        a1 += __shfl_xor(a1, m, 64);
        a2 += __shfl_xor(a2, m, 64);
        a3 += __shfl_xor(a3, m, 64);
    }

    // self-loop: mean attr precomputed (la2)
    const float2 lam = la2[i];
    const float4 xlv = xl4[(i << 4) + q];
    {
        float z0 = xlv.x + fmaf(lam.x, we0.x, fmaf(lam.y, we1.x, xri.x));
        float z1 = xlv.y + fmaf(lam.x, we0.y, fmaf(lam.y, we1.y, xri.y));
        float z2 = xlv.z + fmaf(lam.x, we0.z, fmaf(lam.y, we1.z, xri.z));
        float z3 = xlv.w + fmaf(lam.x, we0.w, fmaf(lam.y, we1.w, xri.w));
        z0 = fmaxf(z0, 0.2f * z0);
        z1 = fmaxf(z1, 0.2f * z1);
        z2 = fmaxf(z2, 0.2f * z2);
        z3 = fmaxf(z3, 0.2f * z3);
        float l = fmaf(z0, av.x, fmaf(z1, av.y, fmaf(z2, av.z, z3 * av.w)));
#pragma unroll
        for (int m = 1; m < LPH; m <<= 1) l += __shfl_xor(l, m, 64);
        float p = exp2f(l);
        den += p;
        a0 = fmaf(p, xlv.x, a0);
        a1 = fmaf(p, xlv.y, a1);
        a2 = fmaf(p, xlv.z, a2);
        a3 = fmaf(p, xlv.w, a3);
    }

    float rd = 1.0f / den;
    const float4 bv = ((const float4*)bias)[q];
    float4 o;
    o.x = fmaxf(fmaf(a0, rd, bv.x), 0.f);
    o.y = fmaxf(fmaf(a1, rd, bv.y), 0.f);
    o.z = fmaxf(fmaf(a2, rd, bv.z), 0.f);
    o.w = fmaxf(fmaf(a3, rd, bv.w), 0.f);

    if (!FUSE_HEADS) {
        if (g == 0) ((float4*)(hout + (size_t)i * 64))[q] = o;
    } else {
        float4 wa01 = ((const float4*)wa)[q * 2];
        float4 wa23 = ((const float4*)wa)[q * 2 + 1];
        float4 wcv  = ((const float4*)wc)[q];
        float d0 = o.x * wa01.x + o.y * wa01.z + o.z * wa23.x + o.w * wa23.z;
        float d1 = o.x * wa01.y + o.y * wa01.w + o.z * wa23.y + o.w * wa23.w;
        float d2 = o.x * wcv.x + o.y * wcv.y + o.z * wcv.z + o.w * wcv.w;
#pragma unroll
        for (int m = 1; m < 16; m <<= 1) {
            d0 += __shfl_xor(d0, m, 64);
            d1 += __shfl_xor(d1, m, 64);
            d2 += __shfl_xor(d2, m, 64);
        }
        if (lane == 0) {
            pout[(size_t)i * 2 + 0] = tanhf(d0 + ba[0]);
            pout[(size_t)i * 2 + 1] = tanhf(d1 + ba[1]);
            pout[(size_t)n * 2 + 2 + i] = d2 + bc[0];
        }
    }
}

// ---------------- launch ---------------------------------------------------

extern "C" void kernel_launch(void* const* d_in, const int* in_sizes, int n_in,
                              void* d_out, int out_size, void* d_ws, size_t ws_size,
                              hipStream_t stream) {
    const float* x    = (const float*)d_in[0];
    const int*   ei   = (const int*)  d_in[1];
    const float* ea   = (const float*)d_in[2];
    const float* w1l  = (const float*)d_in[3];
    const float* b1l  = (const float*)d_in[4];
    const float* w1r  = (const float*)d_in[5];
    const float* b1r  = (const float*)d_in[6];
    const float* w1e  = (const float*)d_in[7];
    const float* att1 = (const float*)d_in[8];
    const float* bias1= (const float*)d_in[9];
    const float* w2l  = (const float*)d_in[10];
    const float* b2l  = (const float*)d_in[11];
    const float* w2r  = (const float*)d_in[12];
    const float* b2r  = (const float*)d_in[13];
    const float* w2e  = (const float*)d_in[14];
    const float* att2 = (const float*)d_in[15];
    const float* bias2= (const float*)d_in[16];
    const float* wa   = (const float*)d_in[17];
    const float* ba   = (const float*)d_in[18];
    const float* wc   = (const float*)d_in[19];
    const float* bc   = (const float*)d_in[20];
    const float* ls   = (const float*)d_in[21];

    const int N = in_sizes[0] / DIN;
    const int E = in_sizes[2] / 2;
    const int* srcr = ei;
    const int* dstr = ei + E;

    const int NB = (N + 255) >> 8;           // node buckets (196)
    const int Ec = (E + 255) / 256;          // edges per chunk
    int cap = (E + NB - 1) / NB;             // bucket capacity, 1.25x mean
    cap = ((cap + cap / 4) + 63) & ~63;

    char* p = (char*)d_ws;
    auto alloc = [&](size_t bytes) -> void* {
        void* r = (void*)p;
        p += (bytes + 255) & ~(size_t)255;
        return r;
    };
    int*    cursor   = (int*)   alloc(256 * 4);
    int*    chunkoff = (int*)   alloc(256 * 256 * 4);
    int*    rank     = (int*)   alloc((size_t)E * 4);
    int2*   rse      = (int2*)  alloc((size_t)N * 8);
    float2* la2      = (float2*)alloc((size_t)N * 8);
    int2*   edges    = (int2*)  alloc(((size_t)NB * cap + 64) * 8);
    float*  xl       = (float*) alloc((size_t)N * F1 * 4);
    float*  xr       = (float*) alloc((size_t)N * F1 * 4);
    float*  h1       = (float*) alloc((size_t)N * F1 * 4);
    float*  h2       = (float*) alloc((size_t)N * F2 * 4);
    // inter (NB*cap*8 ~= 16.6 MB) aliases h1+h2 (25.6 MB); consumed by
    // bucket_csr before h1/h2 are written.
    int2* inter = (int2*)h1;
    (void)ws_size; (void)n_in; (void)out_size;

    hipMemsetAsync(cursor, 0, 256 * 4, stream);

    const int TB = 256;
    int gridGemm = (N + 31) / 32;
    int gridWave = (N + 3) / 4;

    fused_bcount_lin1<<<gridGemm + 256, TB, 0, stream>>>(
        dstr, cursor, chunkoff, rank, E, Ec, NB, gridGemm,
        x, w1l, b1l, w1r, b1r, xl, xr, N);
    scatter_buckets<<<256, 512, 0, stream>>>(srcr, dstr, ea, rank, chunkoff,
                                             inter, E, Ec, NB, cap);
    bucket_csr<<<NB, 512, 0, stream>>>(inter, cursor, rse, la2, edges, NB, N, cap);

    gat_kernel<4, 16, false><<<gridWave, TB, 0, stream>>>(
        xl, xr, rse, la2, edges, w1e, att1, bias1, h1,
        nullptr, nullptr, nullptr, nullptr, nullptr, nullptr, N);
    lin_lr_tiled64<<<gridGemm, TB, 0, stream>>>(h1, w2l, b2l, w2r, b2r, xl, xr, N);
    gat_kernel<2, 32, true><<<gridWave, TB, 0, stream>>>(
        xl, xr, rse, la2, edges, w2e, att2, bias2, h2,
        wa, ba, wc, bc, ls, (float*)d_out, N);
}

// Round 15
// 292.957 us; speedup vs baseline: 1.0575x; 1.0575x over previous
//
#include <hip/hip_runtime.h>
#include <hip/hip_fp16.h>
#include <math.h>

#define DIN   32
#define F1    64   // H1*C1
#define F2    64   // H2*C2

// bf16 round-to-nearest-even pack of two floats into one uint
__device__ __forceinline__ unsigned bf16pack(float a, float b) {
    unsigned ua = __float_as_uint(a);
    unsigned ub = __float_as_uint(b);
    ua = (ua + 0x7FFFu + ((ua >> 16) & 1u)) >> 16;
    ub = (ub + 0x7FFFu + ((ub >> 16) & 1u)) >> 16;
    return ua | (ub << 16);
}

// ---------------- dense-linear body (shared) --------------------------------
// 32-node x 128-output tile, 256 threads, 2x8 micro-tile (16 acc regs).
// xl output stored FP16 (halves the gat gather bytes); xr stays FP32
// (read once per node). R4/R5 lesson: fat micro-tiles spill; cap unroll.
template <int K>
__device__ __forceinline__ void lin_lr_body(int bid,
        const float* __restrict__ x,
        const float* __restrict__ Wl, const float* __restrict__ bl,
        const float* __restrict__ Wr, const float* __restrict__ br,
        __half* __restrict__ xl, float* __restrict__ xr, int n) {
    __shared__ float Ash[32][K + 4];
    __shared__ float Wsh[K][128];
    const int t = threadIdx.x;
    const int node0 = bid * 32;

    for (int idx = t; idx < 32 * (K / 4); idx += 256) {
        int m = idx / (K / 4), kq = idx % (K / 4);
        float4 v = make_float4(0.f, 0.f, 0.f, 0.f);
        if (node0 + m < n) v = ((const float4*)(x + (size_t)(node0 + m) * K))[kq];
        *(float4*)&Ash[m][kq * 4] = v;
    }
    for (int idx = t; idx < K * 32; idx += 256) {
        int k = idx / 32, j4 = idx % 32;
        float4 v = (j4 < 16) ? ((const float4*)(Wl + (size_t)k * 64))[j4]
                             : ((const float4*)(Wr + (size_t)k * 64))[j4 - 16];
        *(float4*)&Wsh[k][j4 * 4] = v;
    }
    __syncthreads();

    const int ty = t >> 4;
    const int tx = t & 15;
    float acc0[8], acc1[8];
#pragma unroll
    for (int j = 0; j < 8; j++) { acc0[j] = 0.f; acc1[j] = 0.f; }

#pragma unroll 4
    for (int k = 0; k < K; k++) {
        float a0 = Ash[ty * 2 + 0][k];
        float a1 = Ash[ty * 2 + 1][k];
        float4 w0 = *(const float4*)&Wsh[k][tx * 8];
        float4 w1 = *(const float4*)&Wsh[k][tx * 8 + 4];
        acc0[0] += a0 * w0.x; acc0[1] += a0 * w0.y;
        acc0[2] += a0 * w0.z; acc0[3] += a0 * w0.w;
        acc0[4] += a0 * w1.x; acc0[5] += a0 * w1.y;
        acc0[6] += a0 * w1.z; acc0[7] += a0 * w1.w;
        acc1[0] += a1 * w0.x; acc1[1] += a1 * w0.y;
        acc1[2] += a1 * w0.z; acc1[3] += a1 * w0.w;
        acc1[4] += a1 * w1.x; acc1[5] += a1 * w1.y;
        acc1[6] += a1 * w1.z; acc1[7] += a1 * w1.w;
    }

    const float* bsrc = (tx < 8) ? bl : br;
    int jb = (tx < 8) ? tx * 8 : (tx - 8) * 8;
    float4 b0 = ((const float4*)(bsrc + jb))[0];
    float4 b1 = ((const float4*)(bsrc + jb))[1];
#pragma unroll
    for (int m = 0; m < 2; m++) {
        int node = node0 + ty * 2 + m;
        if (node >= n) continue;
        const float* ac = (m == 0) ? acc0 : acc1;
        float o0 = ac[0] + b0.x, o1 = ac[1] + b0.y;
        float o2 = ac[2] + b0.z, o3 = ac[3] + b0.w;
        float o4 = ac[4] + b1.x, o5 = ac[5] + b1.y;
        float o6 = ac[6] + b1.z, o7 = ac[7] + b1.w;
        if (tx < 8) {
            __half2 h0 = __floats2half2_rn(o0, o1);
            __half2 h1 = __floats2half2_rn(o2, o3);
            __half2 h2 = __floats2half2_rn(o4, o5);
            __half2 h3 = __floats2half2_rn(o6, o7);
            uint4 pk;
            pk.x = *(unsigned*)&h0; pk.y = *(unsigned*)&h1;
            pk.z = *(unsigned*)&h2; pk.w = *(unsigned*)&h3;
            *((uint4*)(xl + (size_t)node * 64 + jb)) = pk;
        } else {
            float4 f0 = make_float4(o0, o1, o2, o3);
            float4 f1 = make_float4(o4, o5, o6, o7);
            ((float4*)(xr + (size_t)node * 64 + jb))[0] = f0;
            ((float4*)(xr + (size_t)node * 64 + jb))[1] = f1;
        }
    }
}

// ---------------- K1: bucket-count + rank + cursor reserve || lin1 ----------
__global__ __launch_bounds__(256, 2)
void fused_bcount_lin1(const int* __restrict__ dstr, int* __restrict__ cursor,
                       int* __restrict__ chunkoff, int* __restrict__ rank,
                       int E, int Ec, int NB, int gridLin,
                       const float* __restrict__ x,
                       const float* __restrict__ Wl, const float* __restrict__ bl,
                       const float* __restrict__ Wr, const float* __restrict__ br,
                       __half* __restrict__ xl, float* __restrict__ xr, int n) {
    __shared__ int hist[256];
    if ((int)blockIdx.x < gridLin) {
        lin_lr_body<DIN>(blockIdx.x, x, Wl, bl, Wr, br, xl, xr, n);
        return;
    }
    const int blk = blockIdx.x - gridLin;
    const int t = threadIdx.x;
    hist[t] = 0;
    __syncthreads();
    const int s0 = blk * Ec, s1 = min(E, s0 + Ec);
    for (int e = s0 + t; e < s1; e += 256)
        rank[e] = atomicAdd(&hist[dstr[e] >> 8], 1);
    __syncthreads();
    if (t < NB) {
        int h = hist[t];
        chunkoff[blk * 256 + t] = h ? atomicAdd(&cursor[t], h) : 0;
    }
}

// ---------------- K3: scatter into fixed-cap bucket regions -----------------
__global__ __launch_bounds__(512)
void scatter_buckets(const int* __restrict__ srcr, const int* __restrict__ dstr,
                     const float* __restrict__ ea, const int* __restrict__ rank,
                     const int* __restrict__ chunkoff,
                     int2* __restrict__ inter, int E, int Ec, int NB, int cap) {
    __shared__ int colsh[256];
    const int blk = blockIdx.x;
    const int t = threadIdx.x;
    if (t < 256) colsh[t] = (t < NB) ? (t * cap + chunkoff[blk * 256 + t]) : 0;
    __syncthreads();
    const int s0 = blk * Ec, s1 = min(E, s0 + Ec);
    for (int e = s0 + t; e < s1; e += 512) {
        int d = dstr[e];
        float2 v = ((const float2*)ea)[e];
        int2 r;
        r.x = srcr[e] | ((d & 255) << 24);
        r.y = (int)bf16pack(v.x, v.y);
        inter[colsh[d >> 8] + rank[e]] = r;
    }
}

// ---------------- K4: per-bucket CSR finalize (TB=512) ----------------------
// Count loop uses ONE atomic/record (R14's 3-atomic version cost ~10 us).
// la2 (self-loop attr mean) computed AFTER placement by re-reading each
// node's now-contiguous L2-hot range — zero atomics. Gaps zeroed for gat.
__global__ __launch_bounds__(512)
void bucket_csr(const int2* __restrict__ inter, const int* __restrict__ cursor,
                int2* __restrict__ rse, float2* __restrict__ la2,
                int2* __restrict__ edges, int NB, int N, int cap) {
    __shared__ int sh[256];
    __shared__ int cur[256];
    const int b = blockIdx.x, t = threadIdx.x;
    const int bstart = b * cap;
    const int bend = bstart + cursor[b];

    if (t < 256) sh[t] = 0;
    __syncthreads();
    for (int pos = bstart + t; pos < bend; pos += 512)
        atomicAdd(&sh[((unsigned)inter[pos].x) >> 24], 1);
    __syncthreads();
    int cnt_v = 0, myrs = 0;
    if (t < 256) cnt_v = sh[t];
    __syncthreads();
    if (t < 256) sh[t] = cnt_v;
    __syncthreads();
    for (int off = 1; off < 256; off <<= 1) {
        int x = (t >= off && t < 256) ? sh[t - off] : 0;
        __syncthreads();
        if (t < 256) sh[t] += x;
        __syncthreads();
    }
    if (t < 256) {
        int excl = sh[t] - cnt_v;
        cur[t] = excl;
        myrs = bstart + excl;
        int node = b * 256 + t;
        if (node < N) rse[node] = make_int2(myrs, myrs + cnt_v);
    }
    __syncthreads();
    for (int pos = bstart + t; pos < bend; pos += 512) {
        int2 r = inter[pos];
        int k = atomicAdd(&cur[((unsigned)r.x) >> 24], 1);
        r.x &= 0x00FFFFFF;                      // strip dst byte for gat
        edges[bstart + k] = r;
    }
    // zero the gap so gat prefetches past re[] read {src=0, ea=0} records
    int zend = (b + 1) * cap + ((b == NB - 1) ? 64 : 0);
    for (int pos = bend + t; pos < zend; pos += 512)
        edges[pos] = make_int2(0, 0);
    __syncthreads();   // placement stores drained (vmcnt) before re-read
    if (t < 256) {
        int node = b * 256 + t;
        if (node < N) {
            float s0 = 0.f, s1 = 0.f;
            for (int pos = myrs; pos < myrs + cnt_v; pos++) {
                int2 rec = edges[pos];
                s0 += __int_as_float(rec.y << 16);
                s1 += __int_as_float(rec.y & 0xFFFF0000);
            }
            float inv = cnt_v ? 1.0f / (float)cnt_v : 0.f;
            la2[node] = make_float2(s0 * inv, s1 * inv);
        }
    }
}

__global__ __launch_bounds__(256, 2)
void lin_lr_tiled64(const float* __restrict__ x,
                    const float* __restrict__ Wl, const float* __restrict__ bl,
                    const float* __restrict__ Wr, const float* __restrict__ br,
                    __half* __restrict__ xl, float* __restrict__ xr, int n) {
    lin_lr_body<F1>(blockIdx.x, x, Wl, bl, Wr, br, xl, xr, n);
}

// ---------------- GATv2 edge phase ------------------------------------------
// xl gathered as FP16 (128 B/row — halves the dominant gather traffic; +8
// v_cvt/iter). Remainder-FIRST masked head, then mask-free main loop (R14).
// Self-loop mean precomputed (la2). 8 edges/iter, two prefetch streams (R10).
// Max-free online softmax (logits bounded, glorot-scale inputs).
template <int H, int C, bool FUSE_HEADS>
__global__ __launch_bounds__(256)
void gat_kernel(const __half* __restrict__ xl, const float* __restrict__ xr,
                const int2* __restrict__ rse, const float2* __restrict__ la2,
                const int2* __restrict__ edges,
                const float* __restrict__ We, const float* __restrict__ att,
                const float* __restrict__ bias, float* __restrict__ hout,
                const float* __restrict__ wa, const float* __restrict__ ba,
                const float* __restrict__ wc, const float* __restrict__ bc,
                const float* __restrict__ ls, float* __restrict__ pout,
                int n) {
    constexpr int LPH = C / 4;
    if (FUSE_HEADS && blockIdx.x == 0 && threadIdx.x < 2)
        pout[(size_t)n * 2 + threadIdx.x] = expf(ls[threadIdx.x]);
    const int lane = threadIdx.x & 63;
    const int wid = (blockIdx.x * blockDim.x + threadIdx.x) >> 6;
    if (wid >= n) return;
    const int i = wid;
    const int g = lane >> 4;
    const int q = lane & 15;

    const uint2* xlh = (const uint2*)xl;      // 4 halfs per uint2; row = 16
    auto h4tof4 = [](uint2 h) -> float4 {
        float2 lo = __half22float2(*(__half2*)&h.x);
        float2 hi = __half22float2(*(__half2*)&h.y);
        return make_float4(lo.x, lo.y, hi.x, hi.y);
    };
    const float4 xri = ((const float4*)(xr + (size_t)i * 64))[q];
    const float4 we0 = ((const float4*)We)[q];
    const float4 we1 = ((const float4*)(We + 64))[q];
    float4 av = ((const float4*)att)[q];
    const float LOG2E = 1.4426950408889634f;
    av.x *= LOG2E; av.y *= LOG2E; av.z *= LOG2E; av.w *= LOG2E;

    float den = 0.f;
    float a0 = 0.f, a1 = 0.f, a2 = 0.f, a3 = 0.f;

    const int2 se = rse[i];
    const int e0 = se.x, e1 = se.y;
    const int r = (e1 - e0) & 7;

    // ---- masked head: the (deg mod 8) ragged edges, done FIRST ----
    if (r) {
        int2 h0 = edges[e0 + g];
        int2 h1 = edges[e0 + 4 + g];
        float4 xh0 = h4tof4(xlh[(h0.x << 4) + q]);
        float4 xh1 = h4tof4(xlh[(h1.x << 4) + q]);
        const bool v0 = g < r;
        const bool v1 = (4 + g) < r;
        float ea00 = v0 ? __int_as_float(h0.y << 16) : 0.f;
        float ea01 = v0 ? __int_as_float(h0.y & 0xFFFF0000) : 0.f;
        float ea10 = v1 ? __int_as_float(h1.y << 16) : 0.f;
        float ea11 = v1 ? __int_as_float(h1.y & 0xFFFF0000) : 0.f;
        float y0 = xh0.x + fmaf(ea00, we0.x, fmaf(ea01, we1.x, xri.x));
        float y1 = xh0.y + fmaf(ea00, we0.y, fmaf(ea01, we1.y, xri.y));
        float y2 = xh0.z + fmaf(ea00, we0.z, fmaf(ea01, we1.z, xri.z));
        float y3 = xh0.w + fmaf(ea00, we0.w, fmaf(ea01, we1.w, xri.w));
        float u0 = xh1.x + fmaf(ea10, we0.x, fmaf(ea11, we1.x, xri.x));
        float u1 = xh1.y + fmaf(ea10, we0.y, fmaf(ea11, we1.y, xri.y));
        float u2 = xh1.z + fmaf(ea10, we0.z, fmaf(ea11, we1.z, xri.z));
        float u3 = xh1.w + fmaf(ea10, we0.w, fmaf(ea11, we1.w, xri.w));
        y0 = fmaxf(y0, 0.2f * y0); u0 = fmaxf(u0, 0.2f * u0);
        y1 = fmaxf(y1, 0.2f * y1); u1 = fmaxf(u1, 0.2f * u1);
        y2 = fmaxf(y2, 0.2f * y2); u2 = fmaxf(u2, 0.2f * u2);
        y3 = fmaxf(y3, 0.2f * y3); u3 = fmaxf(u3, 0.2f * u3);
        float l0 = fmaf(y0, av.x, fmaf(y1, av.y, fmaf(y2, av.z, y3 * av.w)));
        float l1 = fmaf(u0, av.x, fmaf(u1, av.y, fmaf(u2, av.z, u3 * av.w)));
#pragma unroll
        for (int m = 1; m < LPH; m <<= 1) {
            l0 += __shfl_xor(l0, m, 64);
            l1 += __shfl_xor(l1, m, 64);
        }
        float p0 = v0 ? exp2f(l0) : 0.f;
        float p1 = v1 ? exp2f(l1) : 0.f;
        den += p0 + p1;
        a0 = fmaf(p0, xh0.x, fmaf(p1, xh1.x, a0));
        a1 = fmaf(p0, xh0.y, fmaf(p1, xh1.y, a1));
        a2 = fmaf(p0, xh0.z, fmaf(p1, xh1.z, a2));
        a3 = fmaf(p0, xh0.w, fmaf(p1, xh1.w, a3));
    }

    // ---- mask-free main loop (multiple of 8 edges) ----
    const int em = e0 + r;
    int2 rn0 = edges[em + g];
    int2 rn1 = edges[em + 4 + g];
    uint2 xpn0 = xlh[(rn0.x << 4) + q];
    uint2 xpn1 = xlh[(rn1.x << 4) + q];

    for (int eb = em; eb < e1; eb += 8) {
        int2 r0 = rn0, r1 = rn1;
        float4 xv0 = h4tof4(xpn0);
        float4 xv1 = h4tof4(xpn1);
        rn0 = edges[eb + 8 + g];
        rn1 = edges[eb + 12 + g];
        xpn0 = xlh[(rn0.x << 4) + q];
        xpn1 = xlh[(rn1.x << 4) + q];

        float ea00 = __int_as_float(r0.y << 16);
        float ea01 = __int_as_float(r0.y & 0xFFFF0000);
        float ea10 = __int_as_float(r1.y << 16);
        float ea11 = __int_as_float(r1.y & 0xFFFF0000);

        float y0 = xv0.x + fmaf(ea00, we0.x, fmaf(ea01, we1.x, xri.x));
        float y1 = xv0.y + fmaf(ea00, we0.y, fmaf(ea01, we1.y, xri.y));
        float y2 = xv0.z + fmaf(ea00, we0.z, fmaf(ea01, we1.z, xri.z));
        float y3 = xv0.w + fmaf(ea00, we0.w, fmaf(ea01, we1.w, xri.w));
        float u0 = xv1.x + fmaf(ea10, we0.x, fmaf(ea11, we1.x, xri.x));
        float u1 = xv1.y + fmaf(ea10, we0.y, fmaf(ea11, we1.y, xri.y));
        float u2 = xv1.z + fmaf(ea10, we0.z, fmaf(ea11, we1.z, xri.z));
        float u3 = xv1.w + fmaf(ea10, we0.w, fmaf(ea11, we1.w, xri.w));
        y0 = fmaxf(y0, 0.2f * y0); u0 = fmaxf(u0, 0.2f * u0);
        y1 = fmaxf(y1, 0.2f * y1); u1 = fmaxf(u1, 0.2f * u1);
        y2 = fmaxf(y2, 0.2f * y2); u2 = fmaxf(u2, 0.2f * u2);
        y3 = fmaxf(y3, 0.2f * y3); u3 = fmaxf(u3, 0.2f * u3);
        float l0 = fmaf(y0, av.x, fmaf(y1, av.y, fmaf(y2, av.z, y3 * av.w)));
        float l1 = fmaf(u0, av.x, fmaf(u1, av.y, fmaf(u2, av.z, u3 * av.w)));
#pragma unroll
        for (int m = 1; m < LPH; m <<= 1) {
            l0 += __shfl_xor(l0, m, 64);
            l1 += __shfl_xor(l1, m, 64);
        }
        float p0 = exp2f(l0);
        float p1 = exp2f(l1);
        den += p0 + p1;
        a0 = fmaf(p0, xv0.x, fmaf(p1, xv1.x, a0));
        a1 = fmaf(p0, xv0.y, fmaf(p1, xv1.y, a1));
        a2 = fmaf(p0, xv0.z, fmaf(p1, xv1.z, a2));
        a3 = fmaf(p0, xv0.w, fmaf(p1, xv1.w, a3));
    }

    // merge the 4 edge-slot groups — pure adds
#pragma unroll
    for (int m = 16; m < 64; m <<= 1) {
        den += __shfl_xor(den, m, 64);
        a0 += __shfl_xor(a0, m, 64);
        a1 += __shfl_xor(a1, m, 64);
        a2 += __shfl_xor(a2, m, 64);
        a3 += __shfl_xor(a3, m, 64);
    }

    // self-loop: mean attr precomputed (la2)
    const float2 lam = la2[i];
    const float4 xlv = h4tof4(xlh[(i << 4) + q]);
    {
        float z0 = xlv.x + fmaf(lam.x, we0.x, fmaf(lam.y, we1.x, xri.x));
        float z1 = xlv.y + fmaf(lam.x, we0.y, fmaf(lam.y, we1.y, xri.y));
        float z2 = xlv.z + fmaf(lam.x, we0.z, fmaf(lam.y, we1.z, xri.z));
        float z3 = xlv.w + fmaf(lam.x, we0.w, fmaf(lam.y, we1.w, xri.w));
        z0 = fmaxf(z0, 0.2f * z0);
        z1 = fmaxf(z1, 0.2f * z1);
        z2 = fmaxf(z2, 0.2f * z2);
        z3 = fmaxf(z3, 0.2f * z3);
        float l = fmaf(z0, av.x, fmaf(z1, av.y, fmaf(z2, av.z, z3 * av.w)));
#pragma unroll
        for (int m = 1; m < LPH; m <<= 1) l += __shfl_xor(l, m, 64);
        float p = exp2f(l);
        den += p;
        a0 = fmaf(p, xlv.x, a0);
        a1 = fmaf(p, xlv.y, a1);
        a2 = fmaf(p, xlv.z, a2);
        a3 = fmaf(p, xlv.w, a3);
    }

    float rd = 1.0f / den;
    const float4 bv = ((const float4*)bias)[q];
    float4 o;
    o.x = fmaxf(fmaf(a0, rd, bv.x), 0.f);
    o.y = fmaxf(fmaf(a1, rd, bv.y), 0.f);
    o.z = fmaxf(fmaf(a2, rd, bv.z), 0.f);
    o.w = fmaxf(fmaf(a3, rd, bv.w), 0.f);

    if (!FUSE_HEADS) {
        if (g == 0) ((float4*)(hout + (size_t)i * 64))[q] = o;
    } else {
        float4 wa01 = ((const float4*)wa)[q * 2];
        float4 wa23 = ((const float4*)wa)[q * 2 + 1];
        float4 wcv  = ((const float4*)wc)[q];
        float d0 = o.x * wa01.x + o.y * wa01.z + o.z * wa23.x + o.w * wa23.z;
        float d1 = o.x * wa01.y + o.y * wa01.w + o.z * wa23.y + o.w * wa23.w;
        float d2 = o.x * wcv.x + o.y * wcv.y + o.z * wcv.z + o.w * wcv.w;
#pragma unroll
        for (int m = 1; m < 16; m <<= 1) {
            d0 += __shfl_xor(d0, m, 64);
            d1 += __shfl_xor(d1, m, 64);
            d2 += __shfl_xor(d2, m, 64);
        }
        if (lane == 0) {
            pout[(size_t)i * 2 + 0] = tanhf(d0 + ba[0]);
            pout[(size_t)i * 2 + 1] = tanhf(d1 + ba[1]);
            pout[(size_t)n * 2 + 2 + i] = d2 + bc[0];
        }
    }
}

// ---------------- launch ---------------------------------------------------

extern "C" void kernel_launch(void* const* d_in, const int* in_sizes, int n_in,
                              void* d_out, int out_size, void* d_ws, size_t ws_size,
                              hipStream_t stream) {
    const float* x    = (const float*)d_in[0];
    const int*   ei   = (const int*)  d_in[1];
    const float* ea   = (const float*)d_in[2];
    const float* w1l  = (const float*)d_in[3];
    const float* b1l  = (const float*)d_in[4];
    const float* w1r  = (const float*)d_in[5];
    const float* b1r  = (const float*)d_in[6];
    const float* w1e  = (const float*)d_in[7];
    const float* att1 = (const float*)d_in[8];
    const float* bias1= (const float*)d_in[9];
    const float* w2l  = (const float*)d_in[10];
    const float* b2l  = (const float*)d_in[11];
    const float* w2r  = (const float*)d_in[12];
    const float* b2r  = (const float*)d_in[13];
    const float* w2e  = (const float*)d_in[14];
    const float* att2 = (const float*)d_in[15];
    const float* bias2= (const float*)d_in[16];
    const float* wa   = (const float*)d_in[17];
    const float* ba   = (const float*)d_in[18];
    const float* wc   = (const float*)d_in[19];
    const float* bc   = (const float*)d_in[20];
    const float* ls   = (const float*)d_in[21];

    const int N = in_sizes[0] / DIN;
    const int E = in_sizes[2] / 2;
    const int* srcr = ei;
    const int* dstr = ei + E;

    const int NB = (N + 255) >> 8;           // node buckets (196)
    const int Ec = (E + 255) / 256;          // edges per chunk
    int cap = (E + NB - 1) / NB;             // bucket capacity, 1.25x mean
    cap = ((cap + cap / 4) + 63) & ~63;

    char* p = (char*)d_ws;
    auto alloc = [&](size_t bytes) -> void* {
        void* r = (void*)p;
        p += (bytes + 255) & ~(size_t)255;
        return r;
    };
    int*    cursor   = (int*)   alloc(256 * 4);
    int*    chunkoff = (int*)   alloc(256 * 256 * 4);
    int*    rank     = (int*)   alloc((size_t)E * 4);
    int2*   rse      = (int2*)  alloc((size_t)N * 8);
    float2* la2      = (float2*)alloc((size_t)N * 8);
    int2*   edges    = (int2*)  alloc(((size_t)NB * cap + 64) * 8);
    __half* xl       = (__half*)alloc((size_t)N * F1 * 2);
    float*  xr       = (float*) alloc((size_t)N * F1 * 4);
    float*  h1       = (float*) alloc((size_t)N * F1 * 4);
    float*  h2       = (float*) alloc((size_t)N * F2 * 4);
    // inter (NB*cap*8 ~= 16.6 MB) aliases h1+h2 (25.6 MB); consumed by
    // bucket_csr before h1/h2 are written.
    int2* inter = (int2*)h1;
    (void)ws_size; (void)n_in; (void)out_size;

    hipMemsetAsync(cursor, 0, 256 * 4, stream);

    const int TB = 256;
    int gridGemm = (N + 31) / 32;
    int gridWave = (N + 3) / 4;

    fused_bcount_lin1<<<gridGemm + 256, TB, 0, stream>>>(
        dstr, cursor, chunkoff, rank, E, Ec, NB, gridGemm,
        x, w1l, b1l, w1r, b1r, xl, xr, N);
    scatter_buckets<<<256, 512, 0, stream>>>(srcr, dstr, ea, rank, chunkoff,
                                             inter, E, Ec, NB, cap);
    bucket_csr<<<NB, 512, 0, stream>>>(inter, cursor, rse, la2, edges, NB, N, cap);

    gat_kernel<4, 16, false><<<gridWave, TB, 0, stream>>>(
        xl, xr, rse, la2, edges, w1e, att1, bias1, h1,
        nullptr, nullptr, nullptr, nullptr, nullptr, nullptr, N);
    lin_lr_tiled64<<<gridGemm, TB, 0, stream>>>(h1, w2l, b2l, w2r, b2r, xl, xr, N);
    gat_kernel<2, 32, true><<<gridWave, TB, 0, stream>>>(
        xl, xr, rse, la2, edges, w2e, att2, bias2, h2,
        wa, ba, wc, bc, ls, (float*)d_out, N);
}